// Round 1
// baseline (320.473 us; speedup 1.0000x reference)
//
#include <hip/hip_runtime.h>
#include <stdint.h>

#define HIDDEN 1024
#define INTER  4096
#define ROWS   8192               // 4 * 2048
#define BM     32                 // rows per block
#define BK     64                 // i8 K-elems per step
#define NKSTEP (INTER / BK)       // 64
#define NBLK   (ROWS / BM)        // 256 blocks = 1 per CU
#define BTILE  (HIDDEN * BK)      // 64 KB: one K-step B tile (i8)

typedef int i32x4 __attribute__((ext_vector_type(4)));
typedef const uint32_t __attribute__((address_space(1))) gu32;
typedef uint32_t __attribute__((address_space(3))) lu32;

// sign byte: +1 (0x01) for x>=0, -1 (0xFF) for x<0 — matches both-sides
// convention so i8 MFMA computes the exact signed dot sum(sign(a)*sign(w)).
__device__ __forceinline__ uint32_t sgn4(float4 v) {
    uint32_t b0 = (v.x < 0.f) ? 0xFFu : 0x01u;
    uint32_t b1 = (v.y < 0.f) ? 0xFFu : 0x01u;
    uint32_t b2 = (v.z < 0.f) ? 0xFFu : 0x01u;
    uint32_t b3 = (v.w < 0.f) ? 0xFFu : 0x01u;
    return b0 | (b1 << 8) | (b2 << 16) | (b3 << 24);
}

// ---------------------------------------------------------------------------
// K1: W [1024][4096] f32 -> Bg tiled i8 signs + wscale[h] = mean(|W[h,:]|).
// Bg layout = the exact LDS image per K-step: Bg[t][h][0..63] i8, so the main
// kernel's staging is a pure linear 64KB copy per step (global_load_lds).
// ---------------------------------------------------------------------------
__global__ __launch_bounds__(256)
void pack_w_kernel(const float* __restrict__ W, uint8_t* __restrict__ Bg,
                   float* __restrict__ wscale) {
    int h = blockIdx.x;
    int tid = threadIdx.x;
    int lane = tid & 63, wv = tid >> 6;
    const float4* row = (const float4*)(W + (size_t)h * INTER);
    float asum = 0.f;
    #pragma unroll
    for (int q = 0; q < 4; ++q) {
        int g = q * 256 + tid;                 // float4 index 0..1023 (coalesced)
        float4 v = row[g];
        asum += fabsf(v.x) + fabsf(v.y) + fabsf(v.z) + fabsf(v.w);
        int tt = g >> 4;                        // K-step (16 float4 per 64 elems)
        *(uint32_t*)(Bg + (size_t)tt * BTILE + h * BK + (g & 15) * 4) = sgn4(v);
    }
    #pragma unroll
    for (int off = 32; off > 0; off >>= 1) asum += __shfl_down(asum, off);
    __shared__ float red[4];
    if (lane == 0) red[wv] = asum;
    __syncthreads();
    if (tid == 0) wscale[h] = (red[0] + red[1] + red[2] + red[3]) * (1.0f / INTER);
}

// ---------------------------------------------------------------------------
// K2: i8 MFMA GEMM (BM=32 x full 1024 cols) + bias + residual + LayerNorm.
// 512 threads = 8 waves; wave w owns cols w*128..w*128+128.
// Per K-step per wave: 2 A-frag + 8 B-frag ds_read_b128, 16 mfma 16x16x64 i8.
// LDS: B double-buffered 2x64KB (reused as y[32][1024] f32 in epilogue),
// A double-buffered 2x2KB, + small LN reduction buffers => ~137.5 KB, 1 blk/CU.
// ---------------------------------------------------------------------------
__global__ __launch_bounds__(512, 2)
void main_kernel(const float* __restrict__ hs, const uint8_t* __restrict__ Bg,
                 const float* __restrict__ wscale, const float* __restrict__ bias,
                 const float* __restrict__ clipp, const float* __restrict__ input,
                 const float* __restrict__ gamma, const float* __restrict__ beta,
                 float* __restrict__ out) {
    __shared__ alignas(16) uint8_t sB[2 * BTILE];   // 128 KB; epilogue: y[32][1024]
    __shared__ alignas(16) uint8_t sA[2][BM * BK];  // 4 KB
    __shared__ float red_s[8][BM], red_q[8][BM];
    __shared__ float s_mu[BM], s_rs[BM];

    const int tid  = threadIdx.x;
    const int lane = tid & 63;
    const int wave = tid >> 6;
    const int m0   = blockIdx.x * BM;

    // A staging map: thread -> (row, 4-float col group); linear LDS write.
    const int ar = tid >> 4;                   // 0..31
    const int ac = tid & 15;                   // float4 group within 64 cols
    const int aofs = ar * BK + ac * 4;
    const float* aload_base = hs + (size_t)(m0 + ar) * INTER + ac * 4;

    // Fragment read offsets (contiguous 1KB per wave instr -> conflict-free).
    const int l15 = lane & 15;
    const int kc  = lane >> 4;                 // 16B k-chunk within 64
    int aro[2], bro[8];
    #pragma unroll
    for (int rt = 0; rt < 2; ++rt) aro[rt] = (rt * 16 + l15) * BK + kc * 16;
    #pragma unroll
    for (int ct = 0; ct < 8; ++ct)
        bro[ct] = (wave * 128 + ct * 16 + l15) * BK + kc * 16;

    i32x4 acc[2][8];
    #pragma unroll
    for (int rt = 0; rt < 2; ++rt)
        #pragma unroll
        for (int ct = 0; ct < 8; ++ct) acc[rt][ct] = (i32x4){0, 0, 0, 0};

    // ---- prologue: stage K-step 0 ----
    {
        float4 av = *(const float4*)(aload_base);
        const uint8_t* gs = Bg + wave * 8192 + lane * 16;
        uint8_t* ld = &sB[wave * 8192];
        #pragma unroll
        for (int j = 0; j < 8; ++j)
            __builtin_amdgcn_global_load_lds((gu32*)(gs + j * 1024),
                                             (lu32*)(ld + j * 1024), 16, 0, 0);
        *(uint32_t*)&sA[0][aofs] = sgn4(av);
    }
    __syncthreads();

    // ---- main loop: 2-phase double buffer, one barrier per K-step ----
    for (int t = 0; t < NKSTEP; ++t) {
        const int cur = t & 1;
        const int nxt = cur ^ 1;
        const bool more = (t + 1 < NKSTEP);
        float4 av;
        if (more) {
            av = *(const float4*)(aload_base + (t + 1) * BK);  // issue early (T14)
            const uint8_t* gs = Bg + (size_t)(t + 1) * BTILE + wave * 8192 + lane * 16;
            uint8_t* ld = &sB[nxt * BTILE + wave * 8192];
            #pragma unroll
            for (int j = 0; j < 8; ++j)
                __builtin_amdgcn_global_load_lds((gu32*)(gs + j * 1024),
                                                 (lu32*)(ld + j * 1024), 16, 0, 0);
        }
        const uint8_t* bb = &sB[cur * BTILE];
        i32x4 a0 = *(const i32x4*)&sA[cur][aro[0]];
        i32x4 a1 = *(const i32x4*)&sA[cur][aro[1]];
        #pragma unroll
        for (int ct = 0; ct < 8; ++ct) {
            i32x4 bf = *(const i32x4*)&bb[bro[ct]];
            acc[0][ct] = __builtin_amdgcn_mfma_i32_16x16x64_i8(a0, bf, acc[0][ct], 0, 0, 0);
            acc[1][ct] = __builtin_amdgcn_mfma_i32_16x16x64_i8(a1, bf, acc[1][ct], 0, 0, 0);
        }
        if (more) *(uint32_t*)&sA[nxt][aofs] = sgn4(av);       // write late
        __syncthreads();
    }

    // ---- epilogue: y = clip*wscale*dot + bias + input; fused LayerNorm ----
    float clip = clipp[0];
    float cw[8], bi[8];
    const int hb = wave * 128 + l15;
    #pragma unroll
    for (int ct = 0; ct < 8; ++ct) {
        cw[ct] = clip * wscale[hb + ct * 16];
        bi[ct] = bias[hb + ct * 16];
    }
    float* yl = (float*)sB;                    // [32][1024] f32, sB is dead now
    float sp[2][4] = {}, qp[2][4] = {};
    const int rb = (lane >> 4) * 4;
    #pragma unroll
    for (int rt = 0; rt < 2; ++rt) {
        #pragma unroll
        for (int ct = 0; ct < 8; ++ct) {
            int hcol = hb + ct * 16;
            #pragma unroll
            for (int rg = 0; rg < 4; ++rg) {
                int rl = rt * 16 + rb + rg;
                float v = fmaf((float)acc[rt][ct][rg], cw[ct],
                               bi[ct] + input[(size_t)(m0 + rl) * HIDDEN + hcol]);
                sp[rt][rg] += v;
                qp[rt][rg] += v * v;
                yl[rl * HIDDEN + hcol] = v;
            }
        }
    }
    // reduce across the 16 lanes sharing the same row set (xor within group)
    #pragma unroll
    for (int off = 1; off <= 8; off <<= 1) {
        #pragma unroll
        for (int rt = 0; rt < 2; ++rt)
            #pragma unroll
            for (int rg = 0; rg < 4; ++rg) {
                sp[rt][rg] += __shfl_xor(sp[rt][rg], off);
                qp[rt][rg] += __shfl_xor(qp[rt][rg], off);
            }
    }
    if (l15 == 0) {
        int g = lane >> 4;
        #pragma unroll
        for (int rt = 0; rt < 2; ++rt)
            #pragma unroll
            for (int rg = 0; rg < 4; ++rg) {
                red_s[wave][rt * 16 + g * 4 + rg] = sp[rt][rg];
                red_q[wave][rt * 16 + g * 4 + rg] = qp[rt][rg];
            }
    }
    __syncthreads();
    if (tid < BM) {
        float ss = 0.f, qq = 0.f;
        #pragma unroll
        for (int w = 0; w < 8; ++w) { ss += red_s[w][tid]; qq += red_q[w][tid]; }
        float mu  = ss * (1.0f / HIDDEN);
        float var = fmaf(-mu, mu, qq * (1.0f / HIDDEN));
        s_mu[tid] = mu;
        s_rs[tid] = rsqrtf(var + 1e-12f);
    }
    __syncthreads();

    // coalesced float4 store pass from LDS
    const float4* gmp = (const float4*)gamma;
    const float4* btp = (const float4*)beta;
    const float4* yv  = (const float4*)yl;
    float4* outp = (float4*)(out + (size_t)m0 * HIDDEN);
    #pragma unroll
    for (int j = 0; j < 16; ++j) {
        int f  = j * 512 + tid;                // float4 index in 32x256
        int rl = f >> 8;
        int c4 = f & 255;
        float4 y4 = yv[f];
        float4 g4 = gmp[c4], b4 = btp[c4];
        float mu = s_mu[rl], rs = s_rs[rl];
        float4 o;
        o.x = (y4.x - mu) * rs * g4.x + b4.x;
        o.y = (y4.y - mu) * rs * g4.y + b4.y;
        o.z = (y4.z - mu) * rs * g4.z + b4.z;
        o.w = (y4.w - mu) * rs * g4.w + b4.w;
        outp[f] = o;
    }
}

// ---------------------------------------------------------------------------
extern "C" void kernel_launch(void* const* d_in, const int* in_sizes, int n_in,
                              void* d_out, int out_size, void* d_ws, size_t ws_size,
                              hipStream_t stream) {
    const float* hs    = (const float*)d_in[0];  // [4,2048,4096]
    const float* inp   = (const float*)d_in[1];  // [4,2048,1024]
    const float* W     = (const float*)d_in[2];  // [1024,4096]
    const float* b     = (const float*)d_in[3];  // [1024]
    const float* clip  = (const float*)d_in[4];  // scalar
    const float* gamma = (const float*)d_in[5];  // [1024]
    const float* beta  = (const float*)d_in[6];  // [1024]
    float* out = (float*)d_out;

    uint8_t* Bg   = (uint8_t*)d_ws;                                  // 4 MB
    float* wscale = (float*)((char*)d_ws + (size_t)NKSTEP * BTILE);  // 4 KB

    pack_w_kernel<<<HIDDEN, 256, 0, stream>>>(W, Bg, wscale);
    main_kernel<<<NBLK, 512, 0, stream>>>(hs, Bg, wscale, b, clip,
                                          inp, gamma, beta, out);
}

// Round 2
// 295.377 us; speedup vs baseline: 1.0850x; 1.0850x over previous
//
#include <hip/hip_runtime.h>
#include <stdint.h>

#define HIDDEN 1024
#define INTER  4096
#define ROWS   8192               // 4 * 2048
#define BM     32                 // rows per block
#define BK     64                 // i8 K-elems per step
#define NKSTEP 64                 // INTER / BK
#define NBLK   256                // ROWS / BM = 1 block per CU
#define BTILE  65536              // HIDDEN * BK bytes: one K-step B image

typedef int i32x4 __attribute__((ext_vector_type(4)));
typedef const uint32_t __attribute__((address_space(1))) gu32;
typedef uint32_t __attribute__((address_space(3))) lu32;

// sign byte: +1 (0x01) for x>=0, -1 (0xFF) for x<0.
__device__ __forceinline__ uint32_t sgn4(float4 v) {
    uint32_t b0 = (v.x < 0.f) ? 0xFFu : 0x01u;
    uint32_t b1 = (v.y < 0.f) ? 0xFFu : 0x01u;
    uint32_t b2 = (v.z < 0.f) ? 0xFFu : 0x01u;
    uint32_t b3 = (v.w < 0.f) ? 0xFFu : 0x01u;
    return b0 | (b1 << 8) | (b2 << 16) | (b3 << 24);
}

// ---------------------------------------------------------------------------
// K1: W [1024][4096] f32 -> Bg in FRAGMENT-MAJOR order + wscale.
// Bg byte for (col h, k): (k>>6)*BTILE + (h>>4)*1024 + ((k&63)>>4)*256
//                         + (h&15)*16 + (k&15)
// i.e. per K-step, per 16-col block, lane l's 16B frag (col=cb*16+(l&15),
// k-chunk l>>4) sits at lane*16 — so LDS staging is linear AND the MFMA
// frag ds_read_b128 at base+lane*16 is bank-conflict-free by construction.
// ---------------------------------------------------------------------------
__global__ __launch_bounds__(256)
void pack_w_kernel(const float* __restrict__ W, uint8_t* __restrict__ Bg,
                   float* __restrict__ wscale) {
    int h = blockIdx.x;
    int tid = threadIdx.x;
    int lane = tid & 63, wv = tid >> 6;
    const float4* row = (const float4*)(W + (size_t)h * INTER);
    const uint32_t base_h = (uint32_t)(h >> 4) * 1024u + (uint32_t)(h & 15) * 16u;
    float asum = 0.f;
    #pragma unroll
    for (int q = 0; q < 4; ++q) {
        int g = q * 256 + tid;                 // float4 index 0..1023 (coalesced read)
        float4 v = row[g];
        asum += fabsf(v.x) + fabsf(v.y) + fabsf(v.z) + fabsf(v.w);
        uint32_t off = (uint32_t)(g >> 4) * (uint32_t)BTILE + base_h
                     + (uint32_t)((g & 15) >> 2) * 256u + (uint32_t)(g & 3) * 4u;
        *(uint32_t*)(Bg + off) = sgn4(v);
    }
    #pragma unroll
    for (int off = 32; off > 0; off >>= 1) asum += __shfl_down(asum, off);
    __shared__ float red[4];
    if (lane == 0) red[wv] = asum;
    __syncthreads();
    if (tid == 0) wscale[h] = (red[0] + red[1] + red[2] + red[3]) * (1.0f / INTER);
}

// ---------------------------------------------------------------------------
// K2: i8 MFMA GEMM (32 rows x all 1024 cols) + bias + residual + LayerNorm.
// 512 threads = 8 waves; wave w owns cols w*128..+127 AND loads exactly that
// B region -> B sync is per-wave counted vmcnt only (no barrier, no drain).
// Only the 2KB shared A sign-tile needs one raw s_barrier per K-step.
// Steady state per wave: vmcnt(9) = {1 A-load + 8 B-loads} of tile t+1 stay
// in flight while tile t computes (T4: never drain vmcnt in the main loop).
// ---------------------------------------------------------------------------
__global__ __launch_bounds__(512, 2)
void main_kernel(const float* __restrict__ hs, const uint8_t* __restrict__ Bg,
                 const float* __restrict__ wscale, const float* __restrict__ bias,
                 const float* __restrict__ clipp, const float* __restrict__ input,
                 const float* __restrict__ gamma, const float* __restrict__ beta,
                 float* __restrict__ out) {
    __shared__ alignas(16) uint8_t sB[2 * BTILE];   // 128 KB; epilogue: y[32][1024] f32
    __shared__ alignas(16) uint8_t sA[2 * 2048];    // 4 KB sign tiles (frag-major)
    __shared__ float s_mu[BM], s_rs[BM];

    const int tid  = threadIdx.x;
    const int lane = tid & 63;
    const int wave = tid >> 6;
    const int m0   = blockIdx.x * BM;

    // A staging: thread (r = tid>>4, c4 = tid&15) loads hs float4 -> 4 sign
    // bytes at frag-major LDS address (row r = rt*16+l15, k-chunk c4>>2).
    const int ar = tid >> 4;
    const int ac = tid & 15;
    const int awofs = (ar >> 4) * 1024 + ((ac >> 2) * 16 + (ar & 15)) * 16 + (ac & 3) * 4;
    const float* aload = hs + (size_t)(m0 + ar) * INTER + ac * 4;

    // B addressing: wave-private 8KB region, linear lane*16.
    const uint8_t* bsrc = Bg + wave * 8192 + lane * 16;   // + t*BTILE + j*1024
    uint8_t* bdst0 = sB + wave * 8192;                    // + buf*BTILE + j*1024
    const int fofs = lane * 16;

    i32x4 acc0[8], acc1[8];
    #pragma unroll
    for (int ct = 0; ct < 8; ++ct) {
        acc0[ct] = (i32x4){0, 0, 0, 0};
        acc1[ct] = (i32x4){0, 0, 0, 0};
    }

    // ---- prologue: issue A(0),B(0),A(1),B(1); commit sA[0] ----
    float4 av0 = *(const float4*)(aload);
    #pragma unroll
    for (int j = 0; j < 8; ++j)
        __builtin_amdgcn_global_load_lds((gu32*)(bsrc + j * 1024),
                                         (lu32*)(bdst0 + j * 1024), 16, 0, 0);
    float4 av1 = *(const float4*)(aload + 64);
    #pragma unroll
    for (int j = 0; j < 8; ++j)
        __builtin_amdgcn_global_load_lds((gu32*)(bsrc + BTILE + j * 1024),
                                         (lu32*)(bdst0 + BTILE + j * 1024), 16, 0, 0);
    *(uint32_t*)&sA[awofs] = sgn4(av0);        // compiler waits av0 precisely
    asm volatile("s_waitcnt lgkmcnt(0)" ::: "memory");
    __builtin_amdgcn_s_barrier();

// One K-step. VM=9 keeps tile t+1's {A + 8xB} loads in flight (T4).
#define GEMM_BODY(T, CUR, DO_WRITE, DO_ISSUE, VM, AVW, AVL) do {              \
    asm volatile("s_waitcnt vmcnt(" #VM ")" ::: "memory");                    \
    const uint8_t* bb_ = sB + (CUR) * BTILE + wave * 8192;                    \
    i32x4 a0_ = *(const i32x4*)&sA[(CUR) * 2048 + fofs];                      \
    i32x4 a1_ = *(const i32x4*)&sA[(CUR) * 2048 + 1024 + fofs];               \
    _Pragma("unroll")                                                         \
    for (int ct_ = 0; ct_ < 8; ++ct_) {                                       \
        i32x4 bf_ = *(const i32x4*)&bb_[ct_ * 1024 + fofs];                   \
        acc0[ct_] = __builtin_amdgcn_mfma_i32_16x16x64_i8(a0_, bf_, acc0[ct_], 0, 0, 0); \
        acc1[ct_] = __builtin_amdgcn_mfma_i32_16x16x64_i8(a1_, bf_, acc1[ct_], 0, 0, 0); \
    }                                                                         \
    if (DO_WRITE) *(uint32_t*)&sA[((CUR) ^ 1) * 2048 + awofs] = sgn4(AVW);    \
    asm volatile("s_waitcnt lgkmcnt(0)" ::: "memory");                        \
    if (DO_ISSUE) {                                                           \
        AVL = *(const float4*)(aload + ((T) + 2) * 64);                       \
        _Pragma("unroll")                                                     \
        for (int j_ = 0; j_ < 8; ++j_)                                        \
            __builtin_amdgcn_global_load_lds(                                 \
                (gu32*)(bsrc + (size_t)((T) + 2) * BTILE + j_ * 1024),        \
                (lu32*)(bdst0 + (CUR) * BTILE + j_ * 1024), 16, 0, 0);        \
    }                                                                         \
    __builtin_amdgcn_s_barrier();                                             \
} while (0)

    for (int tt = 0; tt < 31; ++tt) {
        const int t0 = 2 * tt;
        GEMM_BODY(t0,     0, 1, 1, 9, av1, av0);
        GEMM_BODY(t0 + 1, 1, 1, 1, 9, av0, av1);
    }
    GEMM_BODY(62, 0, 1, 0, 9, av1, av0);   // last A write (A(63)), no new loads
    GEMM_BODY(63, 1, 0, 0, 0, av0, av0);   // final tile: full drain
#undef GEMM_BODY

    // ---- epilogue ----
    float clip = clipp[0];
    const int l15 = lane & 15;
    const int hb  = wave * 128 + l15;
    const int rb  = (lane >> 4) * 4;
    float cw[8], bi[8];
    #pragma unroll
    for (int ct = 0; ct < 8; ++ct) {
        cw[ct] = clip * wscale[hb + ct * 16];
        bi[ct] = bias[hb + ct * 16];
    }

    // pass 1: scatter y = cw*dot + bias into LDS (sB is dead)
    float* yl = (float*)sB;                 // [32][1024]
    #pragma unroll
    for (int ct = 0; ct < 8; ++ct) {
        #pragma unroll
        for (int rg = 0; rg < 4; ++rg) {
            yl[(rb + rg) * HIDDEN + hb + ct * 16]      = fmaf((float)acc0[ct][rg], cw[ct], bi[ct]);
            yl[(16 + rb + rg) * HIDDEN + hb + ct * 16] = fmaf((float)acc1[ct][rg], cw[ct], bi[ct]);
        }
    }
    __syncthreads();

    // pass 2: coalesced residual add + row stats (16 threads per row)
    const int erow = tid >> 4;              // 0..31
    const int ecol = tid & 15;
    const float4* in4 = (const float4*)(input + (size_t)(m0 + erow) * HIDDEN);
    float4* ylr = (float4*)(yl + erow * HIDDEN);
    float s = 0.f, q = 0.f;
    #pragma unroll
    for (int i = 0; i < 16; ++i) {
        int f = ecol + i * 16;
        float4 y4 = ylr[f];
        float4 r4 = in4[f];
        y4.x += r4.x; y4.y += r4.y; y4.z += r4.z; y4.w += r4.w;
        s += y4.x + y4.y + y4.z + y4.w;
        q += y4.x * y4.x + y4.y * y4.y + y4.z * y4.z + y4.w * y4.w;
        ylr[f] = y4;
    }
    #pragma unroll
    for (int off = 1; off <= 8; off <<= 1) {
        s += __shfl_xor(s, off);
        q += __shfl_xor(q, off);
    }
    if (ecol == 0) {
        float mu  = s * (1.0f / HIDDEN);
        float var = fmaf(-mu, mu, q * (1.0f / HIDDEN));
        s_mu[erow] = mu;
        s_rs[erow] = rsqrtf(var + 1e-12f);
    }
    __syncthreads();

    // pass 3: coalesced LN transform + store
    const float4* gm4 = (const float4*)gamma;
    const float4* bt4 = (const float4*)beta;
    const float4* yv  = (const float4*)yl;
    float4* outp = (float4*)(out + (size_t)m0 * HIDDEN);
    #pragma unroll
    for (int j = 0; j < 16; ++j) {
        int f  = j * 512 + tid;             // float4 index in 32x256
        int rl = f >> 8;
        int c4 = f & 255;
        float4 y4 = yv[f];
        float4 g4 = gm4[c4], b4 = bt4[c4];
        float mu = s_mu[rl], rs = s_rs[rl];
        float4 o;
        o.x = (y4.x - mu) * rs * g4.x + b4.x;
        o.y = (y4.y - mu) * rs * g4.y + b4.y;
        o.z = (y4.z - mu) * rs * g4.z + b4.z;
        o.w = (y4.w - mu) * rs * g4.w + b4.w;
        outp[f] = o;
    }
}

// ---------------------------------------------------------------------------
extern "C" void kernel_launch(void* const* d_in, const int* in_sizes, int n_in,
                              void* d_out, int out_size, void* d_ws, size_t ws_size,
                              hipStream_t stream) {
    const float* hs    = (const float*)d_in[0];  // [4,2048,4096]
    const float* inp   = (const float*)d_in[1];  // [4,2048,1024]
    const float* W     = (const float*)d_in[2];  // [1024,4096]
    const float* b     = (const float*)d_in[3];  // [1024]
    const float* clip  = (const float*)d_in[4];  // scalar
    const float* gamma = (const float*)d_in[5];  // [1024]
    const float* beta  = (const float*)d_in[6];  // [1024]
    float* out = (float*)d_out;

    uint8_t* Bg   = (uint8_t*)d_ws;                                   // 4 MB
    float* wscale = (float*)((char*)d_ws + (size_t)NKSTEP * BTILE);   // 4 KB

    pack_w_kernel<<<HIDDEN, 256, 0, stream>>>(W, Bg, wscale);
    main_kernel<<<NBLK, 512, 0, stream>>>(hs, Bg, wscale, b, clip,
                                          inp, gamma, beta, out);
}